// Round 16
// baseline (644.402 us; speedup 1.0000x reference)
//
#include <hip/hip_runtime.h>
#include <math.h>

#define NN 50000
#define NE 800000
#define CH 128
#define NG 64
#define BN_EPS 1e-5f
#define POOL_CHUNK 64
#define BKT_SHIFT 9
#define NBKT ((NN + 511) >> 9)              // 98 buckets of 512 nodes
#define PTILE 2048
#define NPART ((NE + PTILE - 1) / PTILE)    // 391 partition blocks
#define CAP 16384                           // per-bucket edge capacity (expect ~8200)
#define AGG_BLKS (NN / 4)                   // 12500 blocks per pass (4 nodes/block)

typedef short bfrag8 __attribute__((ext_vector_type(8)));   // 8 bf16 (4 VGPRs)
typedef float facc4 __attribute__((ext_vector_type(4)));    // 4 fp32 acc

__device__ __forceinline__ float gelu_f(float x) {
    return 0.5f * x * (1.0f + erff(x * 0.70710678118654752440f));
}

// bf16 helpers (RNE pack, bit-exact unpack)
__device__ __forceinline__ unsigned int f2bf(float f) {
    unsigned int u = __float_as_uint(f);
    return (u + 0x7FFFu + ((u >> 16) & 1u)) >> 16;
}
__device__ __forceinline__ unsigned int pack_bf2(float lo, float hi) {
    return (f2bf(hi) << 16) | f2bf(lo);
}
__device__ __forceinline__ float bf_lo(unsigned int v) { return __uint_as_float(v << 16); }
__device__ __forceinline__ float bf_hi(unsigned int v) { return __uint_as_float(v & 0xFFFF0000u); }

// ---------------- pass A: partition edges by dst bucket (capacity-strided, 4B packed)
//                   + W-pack blocks appended ----------------
__global__ __launch_bounds__(256) void part_k(const int* __restrict__ ei,
                                              int* __restrict__ btail,
                                              unsigned int* __restrict__ part,
                                              const float* __restrict__ W0,
                                              const float* __restrict__ W1,
                                              const float* __restrict__ W2,
                                              const float* __restrict__ W3,
                                              const float* __restrict__ W4,
                                              unsigned short* __restrict__ wf) {
    int t = threadIdx.x;
    if (blockIdx.x >= NPART) {
        int wb = blockIdx.x - NPART;            // 0..39
        int which = wb >> 3;
        int u = (wb & 7) * 256 + t;             // 0..2047
        const float* W = (which == 0) ? W0 : (which == 1) ? W1 : (which == 2) ? W2
                       : (which == 3) ? W3 : W4;
        unsigned short* dst_wf = wf + (size_t)which * 16384;
        int nt = u >> 8, kc = (u >> 6) & 3, l = u & 63;
        int kbase = kc * 32 + (l >> 4) * 8;
        int n = nt * 16 + (l & 15);
        unsigned int p[4];
        #pragma unroll
        for (int jj = 0; jj < 4; ++jj) {
            float a = W[(kbase + 2 * jj) * 128 + n];
            float b = W[(kbase + 2 * jj + 1) * 128 + n];
            p[jj] = pack_bf2(a, b);
        }
        *(uint4*)(dst_wf + (size_t)u * 8) = make_uint4(p[0], p[1], p[2], p[3]);
        return;
    }

    __shared__ int lh[NBKT];
    __shared__ int gbase[NBKT];
    int base = blockIdx.x * PTILE;
    if (t < NBKT) lh[t] = 0;
    __syncthreads();
    int s[8], d[8], rk[8];
    #pragma unroll
    for (int i = 0; i < 8; ++i) {
        int e = base + i * 256 + t;
        if (e < NE) {
            s[i] = ei[e];
            d[i] = ei[NE + e];
            rk[i] = atomicAdd(&lh[d[i] >> BKT_SHIFT], 1);
        }
    }
    __syncthreads();
    if (t < NBKT && lh[t]) gbase[t] = t * CAP + atomicAdd(&btail[t], lh[t]);
    __syncthreads();
    #pragma unroll
    for (int i = 0; i < 8; ++i) {
        int e = base + i * 256 + t;
        if (e < NE) {
            int b = d[i] >> BKT_SHIFT;
            unsigned int ld = (unsigned int)(d[i] & 511);
            part[gbase[b] + rk[i]] = (ld << 16) | (unsigned int)s[i];
        }
    }
}

// ---------------- pass B: per-bucket count+scan+emit row_ptr/row_cnt/dinv + scatter ----------------
__global__ __launch_bounds__(256) void cscat2_k(const unsigned int* __restrict__ part,
                                                const int* __restrict__ btail,
                                                int* __restrict__ row_ptr,
                                                int* __restrict__ row_cnt,
                                                float* __restrict__ dinv,
                                                int* __restrict__ csr_src) {
    __shared__ int cnt_l[512];
    __shared__ int off_l[512];
    __shared__ int psc[256];
    int b = blockIdx.x;
    int n0 = b << BKT_SHIFT;
    int t = threadIdx.x;
    cnt_l[t] = 0;
    cnt_l[t + 256] = 0;
    __syncthreads();
    int e0 = b * CAP, e1 = e0 + btail[b];
    for (int e = e0 + t; e < e1; e += 256) {
        int ld = (int)(part[e] >> 16);
        atomicAdd(&cnt_l[ld], 1);
    }
    __syncthreads();
    int c0 = cnt_l[2 * t], c1 = cnt_l[2 * t + 1];
    psc[t] = c0 + c1;
    __syncthreads();
    for (int off = 1; off < 256; off <<= 1) {
        int a = (t >= off) ? psc[t - off] : 0;
        __syncthreads();
        psc[t] += a;
        __syncthreads();
    }
    int excl = (t == 0) ? 0 : psc[t - 1];
    off_l[2 * t] = excl;
    off_l[2 * t + 1] = excl + c0;
    #pragma unroll
    for (int k = 0; k < 2; ++k) {
        int ln = 2 * t + k;
        int n = n0 + ln;
        if (n < NN) {
            int c = (k == 0) ? c0 : c1;
            row_ptr[n] = e0 + off_l[ln];
            row_cnt[n] = c;
            dinv[n] = rsqrtf((float)c + 1.0f);   // +1 = self loop
        }
    }
    __syncthreads();
    cnt_l[t] = 0;
    cnt_l[t + 256] = 0;
    __syncthreads();
    for (int e = e0 + t; e < e1; e += 256) {
        unsigned int p = part[e];
        int s = (int)(p & 0xFFFFu);
        int ld = (int)(p >> 16);
        int pos = e0 + off_l[ld] + atomicAdd(&cnt_l[ld], 1);
        csr_src[pos] = s;
    }
}

// ---------------- MFMA GEMM body; dinv hoisted; split lo/hi channel stores ----------------
__device__ __forceinline__ void gemm_core(unsigned short* Alds, unsigned short* Wlds,
                                          const unsigned short* wfrag,
                                          const float* __restrict__ dinv, int tid,
                                          int row0,
                                          unsigned int* out_lo, unsigned int* out_hi) {
    const int w = tid >> 6;
    const int l = tid & 63;
    const int quad = l >> 4;
    const int m = l & 15;

    float dv[4];
    #pragma unroll
    for (int r = 0; r < 4; ++r) {
        int row = row0 + w * 16 + quad * 4 + r;
        dv[r] = (row < NN) ? dinv[row] : 0.f;
    }

    #pragma unroll
    for (int i = 0; i < 8; ++i) {
        int linear = tid + i * 256;
        ((uint4*)Wlds)[linear] = ((const uint4*)wfrag)[linear];
    }
    __syncthreads();

    facc4 acc[8];
    #pragma unroll
    for (int nt = 0; nt < 8; ++nt) acc[nt] = (facc4){0.f, 0.f, 0.f, 0.f};

    #pragma unroll
    for (int kc = 0; kc < 4; ++kc) {
        bfrag8 a = *((const bfrag8*)(Alds + ((size_t)((w * 4 + kc) * 64 + l)) * 8));
        #pragma unroll
        for (int nt = 0; nt < 8; ++nt) {
            bfrag8 b = *((const bfrag8*)(Wlds + ((size_t)((nt * 4 + kc) * 64 + l)) * 8));
            acc[nt] = __builtin_amdgcn_mfma_f32_16x16x32_bf16(a, b, acc[nt], 0, 0, 0);
        }
    }

    // col = nt*16+m; nt<4 -> lo buffer (ch 0..63), nt>=4 -> hi buffer
    #pragma unroll
    for (int nt = 0; nt < 8; ++nt) {
        unsigned short* So = (unsigned short*)((nt < 4) ? out_lo : out_hi);
        int colh = (nt & 3) * 16 + m;
        #pragma unroll
        for (int r = 0; r < 4; ++r) {
            int row = row0 + w * 16 + quad * 4 + r;
            if (row < NN)
                So[(size_t)row * 64 + colh] = (unsigned short)f2bf(acc[nt][r] * dv[r]);
        }
    }
}

// fp32 input (first conv only, no BN)
__global__ __launch_bounds__(256) void gemm_f32_k(const float* __restrict__ A,
                                                  const unsigned short* __restrict__ wfrag,
                                                  const float* __restrict__ dinv,
                                                  unsigned int* __restrict__ out_lo,
                                                  unsigned int* __restrict__ out_hi) {
    __shared__ unsigned short Alds[8192];
    __shared__ unsigned short Wlds[16384];
    const int tid = threadIdx.x;
    const int row0 = blockIdx.x * 64;
    #pragma unroll
    for (int i = 0; i < 4; ++i) {
        int linear = tid + i * 256;
        int r = linear >> 4;
        int g = linear & 15;
        float4 v0 = make_float4(0.f, 0.f, 0.f, 0.f);
        float4 v1 = make_float4(0.f, 0.f, 0.f, 0.f);
        if (row0 + r < NN) {
            const float4* src = (const float4*)&A[(size_t)(row0 + r) * 128 + g * 8];
            v0 = src[0];
            v1 = src[1];
        }
        int unit = (((r >> 4) * 4 + (g >> 2)) * 64) + ((g & 3) * 16) + (r & 15);
        *(uint4*)(Alds + (size_t)unit * 8) =
            make_uint4(pack_bf2(v0.x, v0.y), pack_bf2(v0.z, v0.w),
                       pack_bf2(v1.x, v1.y), pack_bf2(v1.z, v1.w));
    }
    gemm_core(Alds, Wlds, wfrag, dinv, tid, row0, out_lo, out_hi);
}

// split bf16 input; if ss != null apply gelu(bn(h)) on load
__global__ __launch_bounds__(256) void gemm_bf16_k(const unsigned int* __restrict__ h_lo,
                                                   const unsigned int* __restrict__ h_hi,
                                                   const unsigned short* __restrict__ wfrag,
                                                   const float* __restrict__ ss,
                                                   const float* __restrict__ dinv,
                                                   unsigned int* __restrict__ out_lo,
                                                   unsigned int* __restrict__ out_hi) {
    __shared__ unsigned short Alds[8192];
    __shared__ unsigned short Wlds[16384];
    const int tid = threadIdx.x;
    const int row0 = blockIdx.x * 64;
    #pragma unroll
    for (int i = 0; i < 4; ++i) {
        int linear = tid + i * 256;
        int r = linear >> 4;
        int g = linear & 15;     // global channels g*8..g*8+7; g<8 -> lo
        uint4 v = make_uint4(0u, 0u, 0u, 0u);
        if (row0 + r < NN) {
            v = (g < 8) ? ((const uint4*)h_lo)[(size_t)(row0 + r) * 8 + g]
                        : ((const uint4*)h_hi)[(size_t)(row0 + r) * 8 + (g - 8)];
        }
        if (ss) {
            float4 sc0 = ((const float4*)ss)[g * 2];
            float4 sh0 = ((const float4*)ss)[32 + g * 2];
            float4 sc1 = ((const float4*)ss)[g * 2 + 1];
            float4 sh1 = ((const float4*)ss)[32 + g * 2 + 1];
            float f0 = gelu_f(bf_lo(v.x) * sc0.x + sh0.x);
            float f1 = gelu_f(bf_hi(v.x) * sc0.y + sh0.y);
            float f2 = gelu_f(bf_lo(v.y) * sc0.z + sh0.z);
            float f3 = gelu_f(bf_hi(v.y) * sc0.w + sh0.w);
            float f4 = gelu_f(bf_lo(v.z) * sc1.x + sh1.x);
            float f5 = gelu_f(bf_hi(v.z) * sc1.y + sh1.y);
            float f6 = gelu_f(bf_lo(v.w) * sc1.z + sh1.z);
            float f7 = gelu_f(bf_hi(v.w) * sc1.w + sh1.w);
            v = make_uint4(pack_bf2(f0, f1), pack_bf2(f2, f3),
                           pack_bf2(f4, f5), pack_bf2(f6, f7));
        }
        int unit = (((r >> 4) * 4 + (g >> 2)) * 64) + ((g & 3) * 16) + (r & 15);
        *(uint4*)(Alds + (size_t)unit * 8) = v;
    }
    gemm_core(Alds, Wlds, wfrag, dinv, tid, row0, out_lo, out_hi);
}

// ---------------- CSR aggregation: channel-split 2-pass, 2 edges/load, shfl merge ----------------
// grid = 2*AGG_BLKS; pass = blockIdx >= AGG_BLKS. H rows = 32 uints (64 channels).
__global__ __launch_bounds__(256) void csr_agg_k(const int* __restrict__ row_ptr,
                                                 const int* __restrict__ row_cnt,
                                                 const int* __restrict__ csr_src,
                                                 const unsigned int* __restrict__ Hlo,
                                                 const unsigned int* __restrict__ Hhi,
                                                 const float* __restrict__ bias,
                                                 const float* __restrict__ dinv,
                                                 unsigned int* __restrict__ Olo,
                                                 unsigned int* __restrict__ Ohi,
                                                 float* __restrict__ stats) {
    int pass = (blockIdx.x >= AGG_BLKS) ? 1 : 0;
    int blk = blockIdx.x - pass * AGG_BLKS;
    const unsigned int* H = pass ? Hhi : Hlo;
    unsigned int* O = pass ? Ohi : Olo;

    int node = (blk * 256 + threadIdx.x) >> 6;      // always < NN (AGG_BLKS*4 == NN)
    int lane = threadIdx.x & 63;
    int eh = lane >> 5;          // edge slot 0/1
    int ch = lane & 31;          // uint within 32-uint row

    float a0x = 0.f, a0y = 0.f, a1x = 0.f, a1y = 0.f;
    if (eh == 0) {
        unsigned int hs = H[(size_t)node * 32 + ch];
        a0x = bf_lo(hs);
        a0y = bf_hi(hs);
    }

    int j = row_ptr[node];
    int cnt = row_cnt[node];
    int npairs = cnt >> 1;
    for (; npairs >= 8; npairs -= 8, j += 16) {
        int s[8];
        #pragma unroll
        for (int k = 0; k < 8; ++k) s[k] = csr_src[j + 2 * k + eh];
        unsigned int v[8];
        #pragma unroll
        for (int k = 0; k < 8; ++k) v[k] = H[(size_t)s[k] * 32 + ch];
        #pragma unroll
        for (int k = 0; k < 8; k += 2) {
            a0x += bf_lo(v[k]);     a0y += bf_hi(v[k]);
            a1x += bf_lo(v[k + 1]); a1y += bf_hi(v[k + 1]);
        }
    }
    for (; npairs > 0; --npairs, j += 2) {
        int s = csr_src[j + eh];
        unsigned int v = H[(size_t)s * 32 + ch];
        a0x += bf_lo(v);
        a0y += bf_hi(v);
    }
    if ((cnt & 1) && eh == 0) {
        int s = csr_src[j];
        unsigned int v = H[(size_t)s * 32 + ch];
        a0x += bf_lo(v);
        a0y += bf_hi(v);
    }
    float ax = a0x + a1x;
    float ay = a0y + a1y;
    ax += __shfl_down(ax, 32);
    ay += __shfl_down(ay, 32);

    float ox = 0.f, oy = 0.f;
    if (eh == 0) {
        float di = dinv[node];
        float2 b = ((const float2*)bias)[pass * 32 + ch];
        ox = b.x + di * ax;
        oy = b.y + di * ay;
        O[(size_t)node * 32 + ch] = pack_bf2(ox, oy);
    }

    if (stats) {
        __shared__ float red[512];   // 4 arrays of 128 (4 waves x 32 lanes)
        int wv = threadIdx.x >> 6;
        if (eh == 0) {
            red[wv * 32 + ch]       = ox;
            red[128 + wv * 32 + ch] = ox * ox;
            red[256 + wv * 32 + ch] = oy;
            red[384 + wv * 32 + ch] = oy * oy;
        }
        __syncthreads();
        if (threadIdx.x < 32) {
            int c = threadIdx.x;
            float tsx = red[c] + red[32 + c] + red[64 + c] + red[96 + c];
            float tqx = red[128 + c] + red[160 + c] + red[192 + c] + red[224 + c];
            float tsy = red[256 + c] + red[288 + c] + red[320 + c] + red[352 + c];
            float tqy = red[384 + c] + red[416 + c] + red[448 + c] + red[480 + c];
            float* dstb = stats + (size_t)(blk & 63) * 256;
            atomicAdd(&dstb[pass * 64 + 2 * c], tsx);
            atomicAdd(&dstb[pass * 64 + 2 * c + 1], tsy);
            atomicAdd(&dstb[128 + pass * 64 + 2 * c], tqx);
            atomicAdd(&dstb[128 + pass * 64 + 2 * c + 1], tqy);
        }
    }
}

// ---------------- BN finalize: reduce 64 stat buckets -> scale/shift ----------------
__global__ __launch_bounds__(128) void bn_fin_k(const float* __restrict__ stats,
                                                const float* __restrict__ g,
                                                const float* __restrict__ beta,
                                                float* __restrict__ ss) {
    int c = threadIdx.x;
    float sv = 0.f, qv = 0.f;
    #pragma unroll 8
    for (int i = 0; i < 64; ++i) {
        sv += stats[i * 256 + c];
        qv += stats[i * 256 + 128 + c];
    }
    float mean = sv * (1.0f / NN);
    float var = qv * (1.0f / NN) - mean * mean;
    float sc = g[c] * rsqrtf(var + BN_EPS);
    ss[c] = sc;
    ss[128 + c] = beta[c] - mean * sc;
}

// ---------------- global mean pool sum (split bf16 input) ----------------
__global__ __launch_bounds__(128) void pool_sum_k(const unsigned int* __restrict__ h_lo,
                                                  const unsigned int* __restrict__ h_hi,
                                                  const int* __restrict__ batch,
                                                  float* __restrict__ sums) {
    int r0 = blockIdx.x * POOL_CHUNK;
    int r1 = min(r0 + POOL_CHUNK, NN);
    if (r0 >= NN) return;
    int c = threadIdx.x;
    int cp = c >> 1, hi = c & 1;
    const unsigned int* H = (cp < 32) ? h_lo : h_hi;
    int cpl = cp & 31;
    float acc = 0.f;
    int g = batch[r0];
    for (int r = r0; r < r1; ++r) {
        int gr = batch[r];
        if (gr != g) {
            atomicAdd(&sums[g * 128 + c], acc);
            acc = 0.f;
            g = gr;
        }
        unsigned int v = H[(size_t)r * 32 + cpl];
        acc += hi ? bf_hi(v) : bf_lo(v);
    }
    atomicAdd(&sums[g * 128 + c], acc);
}

__device__ __forceinline__ int lower_bound_dev(const int* __restrict__ a, int n, int key) {
    int lo = 0, hi = n;
    while (lo < hi) {
        int mid = (lo + hi) >> 1;
        if (a[mid] < key) lo = mid + 1; else hi = mid;
    }
    return lo;
}

// ---------------- MLP head (pool-div fused) ----------------
__global__ __launch_bounds__(128) void head_k(const float* __restrict__ psum,
                                              const int* __restrict__ batch,
                                              const float* __restrict__ W0, const float* __restrict__ b0,
                                              const float* __restrict__ W1, const float* __restrict__ b1,
                                              const float* __restrict__ W2, const float* __restrict__ b2,
                                              float* __restrict__ out) {
    __shared__ float r0[128], r1[128];
    int g = blockIdx.x, t = threadIdx.x;
    int a = lower_bound_dev(batch, NN, g);
    int b = lower_bound_dev(batch, NN, g + 1);
    float inv = 1.0f / fmaxf((float)(b - a), 1.0f);
    r0[t] = psum[g * 128 + t] * inv;
    __syncthreads();
    float acc = b0[t];
    for (int k = 0; k < 128; ++k) acc += r0[k] * W0[k * 128 + t];
    r1[t] = gelu_f(acc);
    __syncthreads();
    acc = b1[t];
    for (int k = 0; k < 128; ++k) acc += r1[k] * W1[k * 128 + t];
    float y = gelu_f(acc);
    __syncthreads();
    r0[t] = y;
    __syncthreads();
    if (t < 10) {
        acc = b2[t];
        for (int k = 0; k < 128; ++k) acc += r0[k] * W2[k * 10 + t];
        out[g * 10 + t] = acc;
    }
}

extern "C" void kernel_launch(void* const* d_in, const int* in_sizes, int n_in,
                              void* d_out, int out_size, void* d_ws, size_t ws_size,
                              hipStream_t stream) {
    const float* x      = (const float*)d_in[0];
    const int*   ei     = (const int*)d_in[1];
    const int*   batch  = (const int*)d_in[2];
    const float* Wb0    = (const float*)d_in[4];
    const float* bb0    = (const float*)d_in[5];
    const float* gb0    = (const float*)d_in[6];
    const float* betab0 = (const float*)d_in[7];
    const float* Wb1    = (const float*)d_in[8];
    const float* bb1    = (const float*)d_in[9];
    const float* Wa0    = (const float*)d_in[10];
    const float* ba0    = (const float*)d_in[11];
    const float* ga0    = (const float*)d_in[12];
    const float* bea0   = (const float*)d_in[13];
    const float* Wa1    = (const float*)d_in[14];
    const float* ba1    = (const float*)d_in[15];
    const float* ga1    = (const float*)d_in[16];
    const float* bea1   = (const float*)d_in[17];
    const float* Wa2    = (const float*)d_in[18];
    const float* ba2    = (const float*)d_in[19];
    const float* Wh0    = (const float*)d_in[20];
    const float* bh0    = (const float*)d_in[21];
    const float* Wh1    = (const float*)d_in[22];
    const float* bh1    = (const float*)d_in[23];
    const float* Wh2    = (const float*)d_in[24];
    const float* bh2    = (const float*)d_in[25];
    float* out = (float*)d_out;

    char* ws = (char*)d_ws;
    unsigned int* hwLo = (unsigned int*)ws;             ws += (size_t)NN * 32 * 4;
    unsigned int* hwHi = (unsigned int*)ws;             ws += (size_t)NN * 32 * 4;
    unsigned int* hBlo = (unsigned int*)ws;             ws += (size_t)NN * 32 * 4;
    unsigned int* hBhi = (unsigned int*)ws;             ws += (size_t)NN * 32 * 4;
    unsigned int* hClo = (unsigned int*)ws;             ws += (size_t)NN * 32 * 4;
    unsigned int* hChi = (unsigned int*)ws;             ws += (size_t)NN * 32 * 4;
    float* dinv    = (float*)ws;                        ws += (size_t)NN * 4;
    int*   row_ptr = (int*)ws;                          ws += (size_t)(NN + 4) * 4;
    int*   row_cnt = (int*)ws;                          ws += (size_t)NN * 4;
    int*   csr_src = (int*)ws;                          ws += (size_t)NBKT * CAP * 4;
    unsigned int* part = (unsigned int*)ws;             ws += (size_t)NBKT * CAP * 4;
    unsigned short* wf = (unsigned short*)ws;           ws += (size_t)5 * 16384 * 2;
    float* ssbuf   = (float*)ws;                        ws += 256 * 4;
    // ---- zero region (single memset) ----
    char* zbase = ws;
    int*   btail   = (int*)ws;                          ws += 128 * 4;
    float* stats3  = (float*)ws;                        ws += (size_t)3 * 64 * 256 * 4;
    float* psum    = (float*)ws;                        ws += (size_t)NG * CH * 4;
    size_t zbytes = (size_t)(ws - zbase);

    unsigned short* wfb0 = wf;
    unsigned short* wfb1 = wf + 16384;
    unsigned short* wfa0 = wf + 2 * 16384;
    unsigned short* wfa1 = wf + 3 * 16384;
    unsigned short* wfa2 = wf + 4 * 16384;

    float* st0 = stats3;
    float* st1 = stats3 + 64 * 256;
    float* st2 = stats3 + 2 * 64 * 256;

    hipMemsetAsync(zbase, 0, zbytes, stream);

    // CSR build + W-pack (fused)
    part_k<<<NPART + 40, 256, 0, stream>>>(ei, btail, part, Wb0, Wb1, Wa0, Wa1, Wa2, wf);
    cscat2_k<<<NBKT, 256, 0, stream>>>(part, btail, row_ptr, row_cnt, dinv, csr_src);

    auto agg = [&](const float* b, unsigned int* olo, unsigned int* ohi, float* stats) {
        csr_agg_k<<<2 * AGG_BLKS, 256, 0, stream>>>(row_ptr, row_cnt, csr_src,
                                                    hwLo, hwHi, b, dinv, olo, ohi, stats);
    };
    auto bn_fin = [&](const float* st, const float* g, const float* beta) {
        bn_fin_k<<<1, 128, 0, stream>>>(st, g, beta, ssbuf);
    };

    // conv b0 (fp32 input x)
    gemm_f32_k<<<(NN + 63) / 64, 256, 0, stream>>>(x, wfb0, dinv, hwLo, hwHi);
    agg(bb0, hBlo, hBhi, st0);
    bn_fin(st0, gb0, betab0);
    // conv b1 (BN+GELU fused on load)
    gemm_bf16_k<<<(NN + 63) / 64, 256, 0, stream>>>(hBlo, hBhi, wfb1, ssbuf, dinv, hwLo, hwHi);
    agg(bb1, hClo, hChi, nullptr);
    // conv a0 (no BN on input)
    gemm_bf16_k<<<(NN + 63) / 64, 256, 0, stream>>>(hClo, hChi, wfa0, nullptr, dinv, hwLo, hwHi);
    agg(ba0, hBlo, hBhi, st1);
    bn_fin(st1, ga0, bea0);
    // conv a1
    gemm_bf16_k<<<(NN + 63) / 64, 256, 0, stream>>>(hBlo, hBhi, wfa1, ssbuf, dinv, hwLo, hwHi);
    agg(ba1, hClo, hChi, st2);
    bn_fin(st2, ga1, bea1);
    // conv a2
    gemm_bf16_k<<<(NN + 63) / 64, 256, 0, stream>>>(hClo, hChi, wfa2, ssbuf, dinv, hwLo, hwHi);
    agg(ba2, hBlo, hBhi, nullptr);

    pool_sum_k<<<(NN + POOL_CHUNK - 1) / POOL_CHUNK, 128, 0, stream>>>(hBlo, hBhi, batch, psum);
    head_k<<<NG, 128, 0, stream>>>(psum, batch, Wh0, bh0, Wh1, bh1, Wh2, bh2, out);
}

// Round 17
// 496.840 us; speedup vs baseline: 1.2970x; 1.2970x over previous
//
#include <hip/hip_runtime.h>
#include <math.h>

#define NN 50000
#define NE 800000
#define CH 128
#define NG 64
#define BN_EPS 1e-5f
#define POOL_CHUNK 64
#define BKT_SHIFT 9
#define NBKT ((NN + 511) >> 9)              // 98 buckets of 512 nodes
#define PTILE 2048
#define NPART ((NE + PTILE - 1) / PTILE)    // 391 partition blocks
#define CAP 16384                           // per-bucket edge capacity (expect ~8200)

typedef short bfrag8 __attribute__((ext_vector_type(8)));   // 8 bf16 (4 VGPRs)
typedef float facc4 __attribute__((ext_vector_type(4)));    // 4 fp32 acc

__device__ __forceinline__ float gelu_f(float x) {
    return 0.5f * x * (1.0f + erff(x * 0.70710678118654752440f));
}

// bf16 helpers (RNE pack, bit-exact unpack)
__device__ __forceinline__ unsigned int f2bf(float f) {
    unsigned int u = __float_as_uint(f);
    return (u + 0x7FFFu + ((u >> 16) & 1u)) >> 16;
}
__device__ __forceinline__ unsigned int pack_bf2(float lo, float hi) {
    return (f2bf(hi) << 16) | f2bf(lo);
}
__device__ __forceinline__ float bf_lo(unsigned int v) { return __uint_as_float(v << 16); }
__device__ __forceinline__ float bf_hi(unsigned int v) { return __uint_as_float(v & 0xFFFF0000u); }

// ---------------- pass A: partition edges by dst bucket (capacity-strided, 4B packed)
//                   + W-pack blocks appended (blocks >= NPART do wconv work) ----------------
// packed edge: bits [24:16] = dst within bucket (9b), bits [15:0] = src (NN < 65536)
__global__ __launch_bounds__(256) void part_k(const int* __restrict__ ei,
                                              int* __restrict__ btail,
                                              unsigned int* __restrict__ part,
                                              const float* __restrict__ W0,
                                              const float* __restrict__ W1,
                                              const float* __restrict__ W2,
                                              const float* __restrict__ W3,
                                              const float* __restrict__ W4,
                                              unsigned short* __restrict__ wf) {
    int t = threadIdx.x;
    if (blockIdx.x >= NPART) {
        // ---- W -> bf16 B-fragment-order pack ----
        int wb = blockIdx.x - NPART;            // 0..39
        int which = wb >> 3;
        int u = (wb & 7) * 256 + t;             // 0..2047
        const float* W = (which == 0) ? W0 : (which == 1) ? W1 : (which == 2) ? W2
                       : (which == 3) ? W3 : W4;
        unsigned short* dst_wf = wf + (size_t)which * 16384;
        int nt = u >> 8, kc = (u >> 6) & 3, l = u & 63;
        int kbase = kc * 32 + (l >> 4) * 8;
        int n = nt * 16 + (l & 15);
        unsigned int p[4];
        #pragma unroll
        for (int jj = 0; jj < 4; ++jj) {
            float a = W[(kbase + 2 * jj) * 128 + n];
            float b = W[(kbase + 2 * jj + 1) * 128 + n];
            p[jj] = pack_bf2(a, b);
        }
        *(uint4*)(dst_wf + (size_t)u * 8) = make_uint4(p[0], p[1], p[2], p[3]);
        return;
    }

    __shared__ int lh[NBKT];
    __shared__ int gbase[NBKT];
    int base = blockIdx.x * PTILE;
    if (t < NBKT) lh[t] = 0;
    __syncthreads();
    int s[8], d[8], rk[8];
    #pragma unroll
    for (int i = 0; i < 8; ++i) {
        int e = base + i * 256 + t;
        if (e < NE) {
            s[i] = ei[e];
            d[i] = ei[NE + e];
            rk[i] = atomicAdd(&lh[d[i] >> BKT_SHIFT], 1);
        }
    }
    __syncthreads();
    if (t < NBKT && lh[t]) gbase[t] = t * CAP + atomicAdd(&btail[t], lh[t]);
    __syncthreads();
    #pragma unroll
    for (int i = 0; i < 8; ++i) {
        int e = base + i * 256 + t;
        if (e < NE) {
            int b = d[i] >> BKT_SHIFT;
            unsigned int ld = (unsigned int)(d[i] & 511);
            part[gbase[b] + rk[i]] = (ld << 16) | (unsigned int)s[i];
        }
    }
}

// ---------------- pass B: per-bucket count+scan+emit row_ptr/row_cnt/dinv + scatter ----------------
__global__ __launch_bounds__(256) void cscat2_k(const unsigned int* __restrict__ part,
                                                const int* __restrict__ btail,
                                                int* __restrict__ row_ptr,
                                                int* __restrict__ row_cnt,
                                                float* __restrict__ dinv,
                                                int* __restrict__ csr_src) {
    __shared__ int cnt_l[512];
    __shared__ int off_l[512];
    __shared__ int psc[256];
    int b = blockIdx.x;
    int n0 = b << BKT_SHIFT;
    int t = threadIdx.x;
    cnt_l[t] = 0;
    cnt_l[t + 256] = 0;
    __syncthreads();
    int e0 = b * CAP, e1 = e0 + btail[b];
    for (int e = e0 + t; e < e1; e += 256) {
        int ld = (int)(part[e] >> 16);
        atomicAdd(&cnt_l[ld], 1);
    }
    __syncthreads();
    int c0 = cnt_l[2 * t], c1 = cnt_l[2 * t + 1];
    psc[t] = c0 + c1;
    __syncthreads();
    for (int off = 1; off < 256; off <<= 1) {
        int a = (t >= off) ? psc[t - off] : 0;
        __syncthreads();
        psc[t] += a;
        __syncthreads();
    }
    int excl = (t == 0) ? 0 : psc[t - 1];
    off_l[2 * t] = excl;
    off_l[2 * t + 1] = excl + c0;
    #pragma unroll
    for (int k = 0; k < 2; ++k) {
        int ln = 2 * t + k;
        int n = n0 + ln;
        if (n < NN) {
            int c = (k == 0) ? c0 : c1;
            row_ptr[n] = e0 + off_l[ln];
            row_cnt[n] = c;
            dinv[n] = rsqrtf((float)c + 1.0f);   // +1 = self loop
        }
    }
    __syncthreads();
    cnt_l[t] = 0;
    cnt_l[t + 256] = 0;
    __syncthreads();
    for (int e = e0 + t; e < e1; e += 256) {
        unsigned int p = part[e];
        int s = (int)(p & 0xFFFFu);
        int ld = (int)(p >> 16);
        int pos = e0 + off_l[ld] + atomicAdd(&cnt_l[ld], 1);
        csr_src[pos] = s;
    }
}

// ---------------- MFMA GEMM body; dinv loads hoisted BEFORE MFMA; epilogue scales row r ----------------
__device__ __forceinline__ void gemm_core(unsigned short* Alds, unsigned short* Wlds,
                                          const unsigned short* wfrag,
                                          const float* __restrict__ dinv, int tid,
                                          int row0, unsigned int* out16) {
    const int w = tid >> 6;
    const int l = tid & 63;
    const int quad = l >> 4;
    const int m = l & 15;

    // hoisted: dinv for the 4 rows this lane owns — issues long before epilogue use
    float dv[4];
    #pragma unroll
    for (int r = 0; r < 4; ++r) {
        int row = row0 + w * 16 + quad * 4 + r;
        dv[r] = (row < NN) ? dinv[row] : 0.f;
    }

    #pragma unroll
    for (int i = 0; i < 8; ++i) {
        int linear = tid + i * 256;
        ((uint4*)Wlds)[linear] = ((const uint4*)wfrag)[linear];
    }
    __syncthreads();

    facc4 acc[8];
    #pragma unroll
    for (int nt = 0; nt < 8; ++nt) acc[nt] = (facc4){0.f, 0.f, 0.f, 0.f};

    #pragma unroll
    for (int kc = 0; kc < 4; ++kc) {
        bfrag8 a = *((const bfrag8*)(Alds + ((size_t)((w * 4 + kc) * 64 + l)) * 8));
        #pragma unroll
        for (int nt = 0; nt < 8; ++nt) {
            bfrag8 b = *((const bfrag8*)(Wlds + ((size_t)((nt * 4 + kc) * 64 + l)) * 8));
            acc[nt] = __builtin_amdgcn_mfma_f32_16x16x32_bf16(a, b, acc[nt], 0, 0, 0);
        }
    }

    // C/D layout: col = nt*16+m, row = w*16 + quad*4 + r;  store dinv[row]*acc
    #pragma unroll
    for (int nt = 0; nt < 8; ++nt) {
        #pragma unroll
        for (int r = 0; r < 4; ++r) {
            int row = row0 + w * 16 + quad * 4 + r;
            if (row < NN)
                ((unsigned short*)out16)[(size_t)row * 128 + nt * 16 + m] =
                    (unsigned short)f2bf(acc[nt][r] * dv[r]);
        }
    }
}

// fp32 input (first conv only, no BN)
__global__ __launch_bounds__(256) void gemm_f32_k(const float* __restrict__ A,
                                                  const unsigned short* __restrict__ wfrag,
                                                  const float* __restrict__ dinv,
                                                  unsigned int* __restrict__ out16) {
    __shared__ unsigned short Alds[8192];
    __shared__ unsigned short Wlds[16384];
    const int tid = threadIdx.x;
    const int row0 = blockIdx.x * 64;
    #pragma unroll
    for (int i = 0; i < 4; ++i) {
        int linear = tid + i * 256;
        int r = linear >> 4;
        int g = linear & 15;
        float4 v0 = make_float4(0.f, 0.f, 0.f, 0.f);
        float4 v1 = make_float4(0.f, 0.f, 0.f, 0.f);
        if (row0 + r < NN) {
            const float4* src = (const float4*)&A[(size_t)(row0 + r) * 128 + g * 8];
            v0 = src[0];
            v1 = src[1];
        }
        int unit = (((r >> 4) * 4 + (g >> 2)) * 64) + ((g & 3) * 16) + (r & 15);
        *(uint4*)(Alds + (size_t)unit * 8) =
            make_uint4(pack_bf2(v0.x, v0.y), pack_bf2(v0.z, v0.w),
                       pack_bf2(v1.x, v1.y), pack_bf2(v1.z, v1.w));
    }
    gemm_core(Alds, Wlds, wfrag, dinv, tid, row0, out16);
}

// bf16 input; if ss != null apply gelu(bn(h)) on load
__global__ __launch_bounds__(256) void gemm_bf16_k(const unsigned int* __restrict__ h16,
                                                   const unsigned short* __restrict__ wfrag,
                                                   const float* __restrict__ ss,
                                                   const float* __restrict__ dinv,
                                                   unsigned int* __restrict__ out16) {
    __shared__ unsigned short Alds[8192];
    __shared__ unsigned short Wlds[16384];
    const int tid = threadIdx.x;
    const int row0 = blockIdx.x * 64;
    #pragma unroll
    for (int i = 0; i < 4; ++i) {
        int linear = tid + i * 256;
        int r = linear >> 4;
        int g = linear & 15;
        uint4 v = make_uint4(0u, 0u, 0u, 0u);
        if (row0 + r < NN)
            v = ((const uint4*)h16)[(size_t)(row0 + r) * 16 + g];
        if (ss) {
            float4 sc0 = ((const float4*)ss)[g * 2];
            float4 sh0 = ((const float4*)ss)[32 + g * 2];
            float4 sc1 = ((const float4*)ss)[g * 2 + 1];
            float4 sh1 = ((const float4*)ss)[32 + g * 2 + 1];
            float f0 = gelu_f(bf_lo(v.x) * sc0.x + sh0.x);
            float f1 = gelu_f(bf_hi(v.x) * sc0.y + sh0.y);
            float f2 = gelu_f(bf_lo(v.y) * sc0.z + sh0.z);
            float f3 = gelu_f(bf_hi(v.y) * sc0.w + sh0.w);
            float f4 = gelu_f(bf_lo(v.z) * sc1.x + sh1.x);
            float f5 = gelu_f(bf_hi(v.z) * sc1.y + sh1.y);
            float f6 = gelu_f(bf_lo(v.w) * sc1.z + sh1.z);
            float f7 = gelu_f(bf_hi(v.w) * sc1.w + sh1.w);
            v = make_uint4(pack_bf2(f0, f1), pack_bf2(f2, f3),
                           pack_bf2(f4, f5), pack_bf2(f6, f7));
        }
        int unit = (((r >> 4) * 4 + (g >> 2)) * 64) + ((g & 3) * 16) + (r & 15);
        *(uint4*)(Alds + (size_t)unit * 8) = v;
    }
    gemm_core(Alds, Wlds, wfrag, dinv, tid, row0, out16);
}

// ---------------- CSR aggregation: one wave per node, add-only 16-deep gather ----------------
// hw16 rows are pre-scaled by dinv[row]; out = bias + dinv[node]*(hw16[node] + sum hw16[src])
// stats (nullable): 64 buckets x 256 floats ([ch sums 0..127][ch sumsq 128..255])
__global__ __launch_bounds__(256) void csr_agg_k(const int* __restrict__ row_ptr,
                                                 const int* __restrict__ row_cnt,
                                                 const int* __restrict__ csr_src,
                                                 const unsigned int* __restrict__ hw16,
                                                 const float* __restrict__ bias,
                                                 const float* __restrict__ dinv,
                                                 unsigned int* __restrict__ out16,
                                                 float* __restrict__ stats) {
    int node = (blockIdx.x * 256 + threadIdx.x) >> 6;
    int lane = threadIdx.x & 63;
    float ox = 0.f, oy = 0.f;

    if (node < NN) {
        float di = dinv[node];
        float2 b = ((const float2*)bias)[lane];
        unsigned int hs = hw16[(size_t)node * 64 + lane];
        float a0x = bf_lo(hs), a0y = bf_hi(hs);
        float a1x = 0.f, a1y = 0.f;
        float a2x = 0.f, a2y = 0.f;
        float a3x = 0.f, a3y = 0.f;

        int j = row_ptr[node];
        int j1 = j + row_cnt[node];
        for (; j + 15 < j1; j += 16) {
            int s[16];
            #pragma unroll
            for (int k = 0; k < 16; ++k) s[k] = csr_src[j + k];
            unsigned int v[16];
            #pragma unroll
            for (int k = 0; k < 16; ++k) v[k] = hw16[(size_t)s[k] * 64 + lane];
            #pragma unroll
            for (int k = 0; k < 16; k += 8) {
                a0x += bf_lo(v[k + 0]) + bf_lo(v[k + 1]);
                a0y += bf_hi(v[k + 0]) + bf_hi(v[k + 1]);
                a1x += bf_lo(v[k + 2]) + bf_lo(v[k + 3]);
                a1y += bf_hi(v[k + 2]) + bf_hi(v[k + 3]);
                a2x += bf_lo(v[k + 4]) + bf_lo(v[k + 5]);
                a2y += bf_hi(v[k + 4]) + bf_hi(v[k + 5]);
                a3x += bf_lo(v[k + 6]) + bf_lo(v[k + 7]);
                a3y += bf_hi(v[k + 6]) + bf_hi(v[k + 7]);
            }
        }
        for (; j + 3 < j1; j += 4) {
            int s0 = csr_src[j], s1 = csr_src[j + 1];
            int s2 = csr_src[j + 2], s3 = csr_src[j + 3];
            unsigned int v0 = hw16[(size_t)s0 * 64 + lane];
            unsigned int v1 = hw16[(size_t)s1 * 64 + lane];
            unsigned int v2 = hw16[(size_t)s2 * 64 + lane];
            unsigned int v3 = hw16[(size_t)s3 * 64 + lane];
            a0x += bf_lo(v0) + bf_lo(v1);
            a0y += bf_hi(v0) + bf_hi(v1);
            a1x += bf_lo(v2) + bf_lo(v3);
            a1y += bf_hi(v2) + bf_hi(v3);
        }
        for (; j < j1; ++j) {
            int s = csr_src[j];
            unsigned int v = hw16[(size_t)s * 64 + lane];
            a0x += bf_lo(v);
            a0y += bf_hi(v);
        }
        ox = b.x + di * ((a0x + a1x) + (a2x + a3x));
        oy = b.y + di * ((a0y + a1y) + (a2y + a3y));
        out16[(size_t)node * 64 + lane] = pack_bf2(ox, oy);
    }

    if (stats) {
        __shared__ float red[1024];   // 4 arrays x 256
        int t = threadIdx.x;
        red[t]       = ox;
        red[256 + t] = ox * ox;
        red[512 + t] = oy;
        red[768 + t] = oy * oy;
        __syncthreads();
        if (t < 64) {
            float tsx = red[t] + red[64 + t] + red[128 + t] + red[192 + t];
            float tqx = red[256 + t] + red[320 + t] + red[384 + t] + red[448 + t];
            float tsy = red[512 + t] + red[576 + t] + red[640 + t] + red[704 + t];
            float tqy = red[768 + t] + red[832 + t] + red[896 + t] + red[960 + t];
            float* dst = stats + (size_t)(blockIdx.x & 63) * 256;
            atomicAdd(&dst[2 * t], tsx);
            atomicAdd(&dst[2 * t + 1], tsy);
            atomicAdd(&dst[128 + 2 * t], tqx);
            atomicAdd(&dst[129 + 2 * t], tqy);
        }
    }
}

// ---------------- BN finalize: reduce 64 stat buckets -> scale/shift ----------------
__global__ __launch_bounds__(128) void bn_fin_k(const float* __restrict__ stats,
                                                const float* __restrict__ g,
                                                const float* __restrict__ beta,
                                                float* __restrict__ ss) {
    int c = threadIdx.x;
    float sv = 0.f, qv = 0.f;
    #pragma unroll 8
    for (int i = 0; i < 64; ++i) {
        sv += stats[i * 256 + c];
        qv += stats[i * 256 + 128 + c];
    }
    float mean = sv * (1.0f / NN);
    float var = qv * (1.0f / NN) - mean * mean;
    float sc = g[c] * rsqrtf(var + BN_EPS);
    ss[c] = sc;
    ss[128 + c] = beta[c] - mean * sc;
}

// ---------------- global mean pool sum (bf16 input) ----------------
__global__ __launch_bounds__(128) void pool_sum_k(const unsigned int* __restrict__ h16,
                                                  const int* __restrict__ batch,
                                                  float* __restrict__ sums) {
    int r0 = blockIdx.x * POOL_CHUNK;
    int r1 = min(r0 + POOL_CHUNK, NN);
    if (r0 >= NN) return;
    int c = threadIdx.x;
    int cp = c >> 1, hi = c & 1;
    float acc = 0.f;
    int g = batch[r0];
    for (int r = r0; r < r1; ++r) {
        int gr = batch[r];
        if (gr != g) {
            atomicAdd(&sums[g * 128 + c], acc);
            acc = 0.f;
            g = gr;
        }
        unsigned int v = h16[(size_t)r * 64 + cp];
        acc += hi ? bf_hi(v) : bf_lo(v);
    }
    atomicAdd(&sums[g * 128 + c], acc);
}

__device__ __forceinline__ int lower_bound_dev(const int* __restrict__ a, int n, int key) {
    int lo = 0, hi = n;
    while (lo < hi) {
        int mid = (lo + hi) >> 1;
        if (a[mid] < key) lo = mid + 1; else hi = mid;
    }
    return lo;
}

// ---------------- MLP head (pool-div fused) ----------------
__global__ __launch_bounds__(128) void head_k(const float* __restrict__ psum,
                                              const int* __restrict__ batch,
                                              const float* __restrict__ W0, const float* __restrict__ b0,
                                              const float* __restrict__ W1, const float* __restrict__ b1,
                                              const float* __restrict__ W2, const float* __restrict__ b2,
                                              float* __restrict__ out) {
    __shared__ float r0[128], r1[128];
    int g = blockIdx.x, t = threadIdx.x;
    int a = lower_bound_dev(batch, NN, g);
    int b = lower_bound_dev(batch, NN, g + 1);
    float inv = 1.0f / fmaxf((float)(b - a), 1.0f);
    r0[t] = psum[g * 128 + t] * inv;
    __syncthreads();
    float acc = b0[t];
    for (int k = 0; k < 128; ++k) acc += r0[k] * W0[k * 128 + t];
    r1[t] = gelu_f(acc);
    __syncthreads();
    acc = b1[t];
    for (int k = 0; k < 128; ++k) acc += r1[k] * W1[k * 128 + t];
    float y = gelu_f(acc);
    __syncthreads();
    r0[t] = y;
    __syncthreads();
    if (t < 10) {
        acc = b2[t];
        for (int k = 0; k < 128; ++k) acc += r0[k] * W2[k * 10 + t];
        out[g * 10 + t] = acc;
    }
}

extern "C" void kernel_launch(void* const* d_in, const int* in_sizes, int n_in,
                              void* d_out, int out_size, void* d_ws, size_t ws_size,
                              hipStream_t stream) {
    const float* x      = (const float*)d_in[0];
    const int*   ei     = (const int*)d_in[1];
    const int*   batch  = (const int*)d_in[2];
    const float* Wb0    = (const float*)d_in[4];
    const float* bb0    = (const float*)d_in[5];
    const float* gb0    = (const float*)d_in[6];
    const float* betab0 = (const float*)d_in[7];
    const float* Wb1    = (const float*)d_in[8];
    const float* bb1    = (const float*)d_in[9];
    const float* Wa0    = (const float*)d_in[10];
    const float* ba0    = (const float*)d_in[11];
    const float* ga0    = (const float*)d_in[12];
    const float* bea0   = (const float*)d_in[13];
    const float* Wa1    = (const float*)d_in[14];
    const float* ba1    = (const float*)d_in[15];
    const float* ga1    = (const float*)d_in[16];
    const float* bea1   = (const float*)d_in[17];
    const float* Wa2    = (const float*)d_in[18];
    const float* ba2    = (const float*)d_in[19];
    const float* Wh0    = (const float*)d_in[20];
    const float* bh0    = (const float*)d_in[21];
    const float* Wh1    = (const float*)d_in[22];
    const float* bh1    = (const float*)d_in[23];
    const float* Wh2    = (const float*)d_in[24];
    const float* bh2    = (const float*)d_in[25];
    float* out = (float*)d_out;

    char* ws = (char*)d_ws;
    unsigned int* hw16 = (unsigned int*)ws;             ws += (size_t)NN * 64 * 4;   // GEMM out (bf16x2, dinv-scaled)
    unsigned int* hB   = (unsigned int*)ws;             ws += (size_t)NN * 64 * 4;   // conv out (bf16x2)
    unsigned int* hC   = (unsigned int*)ws;             ws += (size_t)NN * 64 * 4;
    float* dinv    = (float*)ws;                        ws += (size_t)NN * 4;
    int*   row_ptr = (int*)ws;                          ws += (size_t)(NN + 4) * 4;
    int*   row_cnt = (int*)ws;                          ws += (size_t)NN * 4;
    int*   csr_src = (int*)ws;                          ws += (size_t)NBKT * CAP * 4;  // strided index space
    unsigned int* part = (unsigned int*)ws;             ws += (size_t)NBKT * CAP * 4;  // 4B packed edges
    unsigned short* wf = (unsigned short*)ws;           ws += (size_t)5 * 16384 * 2;
    float* ssbuf   = (float*)ws;                        ws += 256 * 4;
    // ---- zero region (single memset) ----
    char* zbase = ws;
    int*   btail   = (int*)ws;                          ws += 128 * 4;
    float* stats3  = (float*)ws;                        ws += (size_t)3 * 64 * 256 * 4;
    float* psum    = (float*)ws;                        ws += (size_t)NG * CH * 4;
    size_t zbytes = (size_t)(ws - zbase);

    unsigned short* wfb0 = wf;
    unsigned short* wfb1 = wf + 16384;
    unsigned short* wfa0 = wf + 2 * 16384;
    unsigned short* wfa1 = wf + 3 * 16384;
    unsigned short* wfa2 = wf + 4 * 16384;

    float* st0 = stats3;
    float* st1 = stats3 + 64 * 256;
    float* st2 = stats3 + 2 * 64 * 256;

    hipMemsetAsync(zbase, 0, zbytes, stream);

    // CSR build + W-pack (fused): capacity-strided buckets, 4B packed partition
    part_k<<<NPART + 40, 256, 0, stream>>>(ei, btail, part, Wb0, Wb1, Wa0, Wa1, Wa2, wf);
    cscat2_k<<<NBKT, 256, 0, stream>>>(part, btail, row_ptr, row_cnt, dinv, csr_src);

    auto agg = [&](const float* b, unsigned int* o, float* stats) {
        csr_agg_k<<<(NN * 64 + 255) / 256, 256, 0, stream>>>(row_ptr, row_cnt, csr_src,
                                                             hw16, b, dinv, o, stats);
    };
    auto bn_fin = [&](const float* st, const float* g, const float* beta) {
        bn_fin_k<<<1, 128, 0, stream>>>(st, g, beta, ssbuf);
    };

    // conv b0 (fp32 input x)
    gemm_f32_k<<<(NN + 63) / 64, 256, 0, stream>>>(x, wfb0, dinv, hw16);
    agg(bb0, hB, st0);
    bn_fin(st0, gb0, betab0);
    // conv b1 (BN+GELU fused on load)
    gemm_bf16_k<<<(NN + 63) / 64, 256, 0, stream>>>(hB, wfb1, ssbuf, dinv, hw16);
    agg(bb1, hC, nullptr);
    // conv a0 (no BN on input)
    gemm_bf16_k<<<(NN + 63) / 64, 256, 0, stream>>>(hC, wfa0, nullptr, dinv, hw16);
    agg(ba0, hB, st1);
    bn_fin(st1, ga0, bea0);
    // conv a1
    gemm_bf16_k<<<(NN + 63) / 64, 256, 0, stream>>>(hB, wfa1, ssbuf, dinv, hw16);
    agg(ba1, hC, st2);
    bn_fin(st2, ga1, bea1);
    // conv a2
    gemm_bf16_k<<<(NN + 63) / 64, 256, 0, stream>>>(hC, wfa2, ssbuf, dinv, hw16);
    agg(ba2, hB, nullptr);

    pool_sum_k<<<(NN + POOL_CHUNK - 1) / POOL_CHUNK, 128, 0, stream>>>(hB, batch, psum);
    head_k<<<NG, 128, 0, stream>>>(psum, batch, Wh0, bh0, Wh1, bh1, Wh2, bh2, out);
}